// Round 10
// baseline (243.926 us; speedup 1.0000x reference)
//
#include <hip/hip_runtime.h>
#include <hip/hip_cooperative_groups.h>

namespace cg = cooperative_groups;

#define EPS_BN 1e-5f
#define FDIM 512        // face feature dim
#define F4   128        // FDIM/4
#define HDIM 32
#define NB_XS 64        // xsums partial blocks
#define GB_MAX 1024     // cooperative grid cap

// ---------------------------------------------------------------------------
__device__ __forceinline__ int dot4i8(unsigned a, unsigned b) {
#if __has_builtin(__builtin_amdgcn_sdot4)
    return __builtin_amdgcn_sdot4((int)a, (int)b, 0, false);
#else
    int s;
    s  = (int)(signed char)(a      ) * (int)(signed char)(b      );
    s += (int)(signed char)(a >>  8) * (int)(signed char)(b >>  8);
    s += (int)(signed char)(a >> 16) * (int)(signed char)(b >> 16);
    s += (int)(signed char)(a >> 24) * (int)(signed char)(b >> 24);
    return s;
#endif
}

struct NodeSmem {
    float W2[HDIM*HDIM];
    float W1[2*HDIM], b1v[HDIM], a[HDIM], bsh[HDIM];
    float v[HDIM], w0v[HDIM], b2v[HDIM];
    float c, alpha;
    float xsl[5];
};

// ---------------------------------------------------------------------------
// quant: one wave per row, grid-stride over waves. Also zeroes deg.
// ---------------------------------------------------------------------------
__device__ __forceinline__
void quant_rows(const float* __restrict__ face, uint2* __restrict__ qrows,
                float* __restrict__ scales, float* __restrict__ deg,
                int n, int wid0, int wstride, int lane) {
    for (int row = wid0; row < n; row += wstride) {
        const float4* f4 = (const float4*)face + (size_t)row * F4;
        float4 a = f4[lane];
        float4 b = f4[lane + 64];
        float ss = a.x*a.x + a.y*a.y + a.z*a.z + a.w*a.w
                 + b.x*b.x + b.y*b.y + b.z*b.z + b.w*b.w;
        float mx = fmaxf(fmaxf(fmaxf(fabsf(a.x), fabsf(a.y)),
                               fmaxf(fabsf(a.z), fabsf(a.w))),
                         fmaxf(fmaxf(fabsf(b.x), fabsf(b.y)),
                               fmaxf(fabsf(b.z), fabsf(b.w))));
        #pragma unroll
        for (int off = 32; off > 0; off >>= 1) {
            ss += __shfl_xor(ss, off);
            mx  = fmaxf(mx, __shfl_xor(mx, off));
        }
        float rn = rsqrtf(ss + 1e-12f);
        float qs = (mx > 0.f) ? 127.0f / mx : 0.f;
        unsigned da =  ((unsigned)(__float2int_rn(a.x*qs) & 255))
                    | (((unsigned)(__float2int_rn(a.y*qs) & 255)) << 8)
                    | (((unsigned)(__float2int_rn(a.z*qs) & 255)) << 16)
                    | (((unsigned)(__float2int_rn(a.w*qs) & 255)) << 24);
        unsigned db =  ((unsigned)(__float2int_rn(b.x*qs) & 255))
                    | (((unsigned)(__float2int_rn(b.y*qs) & 255)) << 8)
                    | (((unsigned)(__float2int_rn(b.z*qs) & 255)) << 16)
                    | (((unsigned)(__float2int_rn(b.w*qs) & 255)) << 24);
        qrows[(size_t)row * 64 + lane] = make_uint2(da, db);
        if (lane == 0) {
            scales[row] = mx * rn * (1.0f / 127.0f);
            deg[row]    = 0.f;
        }
    }
}

// ---------------------------------------------------------------------------
// xsums: block xbid of NB_XS writes part[xbid*5 .. +5)
// ---------------------------------------------------------------------------
__device__ __forceinline__
void xsums_block(const float* __restrict__ x, float* __restrict__ part,
                 int n, int xbid, int tid) {
    __shared__ float red[4][5];
    float s0=0.f, s1=0.f, s00=0.f, s01=0.f, s11=0.f;
    for (int i = xbid * 256 + tid; i < n; i += NB_XS * 256) {
        float2 xv = ((const float2*)x)[i];
        s0  += xv.x;       s1  += xv.y;
        s00 += xv.x*xv.x;  s01 += xv.x*xv.y;  s11 += xv.y*xv.y;
    }
    #pragma unroll
    for (int off = 32; off > 0; off >>= 1) {
        s0  += __shfl_xor(s0,  off);
        s1  += __shfl_xor(s1,  off);
        s00 += __shfl_xor(s00, off);
        s01 += __shfl_xor(s01, off);
        s11 += __shfl_xor(s11, off);
    }
    int lane = tid & 63, w = tid >> 6;
    if (lane == 0) {
        red[w][0]=s0; red[w][1]=s1; red[w][2]=s00; red[w][3]=s01; red[w][4]=s11;
    }
    __syncthreads();
    if (tid < 5)
        part[xbid * 5 + tid] = red[0][tid] + red[1][tid]
                             + red[2][tid] + red[3][tid];
}

// ---------------------------------------------------------------------------
// node: param recompute from part, then encoder for chunks c0, c0+cstride, ...
// ---------------------------------------------------------------------------
__device__ __forceinline__
void node_work(NodeSmem* s, const float* __restrict__ x,
               const float* __restrict__ W1, const float* __restrict__ b1,
               const float* __restrict__ gamma, const float* __restrict__ beta,
               const float* __restrict__ alpha,
               const float* __restrict__ W2, const float* __restrict__ b2,
               const float* __restrict__ w0,
               const float* __restrict__ Wg, const float* __restrict__ bg,
               const float* __restrict__ wf,
               const float* __restrict__ b0, const float* __restrict__ bf,
               const float* __restrict__ part,
               float* __restrict__ sarr, float* __restrict__ out,
               int n, int tid, int c0, int cstride) {
    for (int i = tid; i < HDIM*HDIM; i += 256) s->W2[i] = W2[i];
    if (tid < 2*HDIM) s->W1[tid] = W1[tid];
    if (tid < 5) {
        float acc = 0.f;
        for (int i = 0; i < NB_XS; ++i) acc += part[i * 5 + tid];
        s->xsl[tid] = acc;
    }
    __syncthreads();
    if (tid < HDIM) {
        float invN = 1.0f / (float)n;
        float m0 = s->xsl[0]*invN, m1 = s->xsl[1]*invN;
        float c00 = s->xsl[2]*invN - m0*m0;
        float c01 = s->xsl[3]*invN - m0*m1;
        float c11 = s->xsl[4]*invN - m1*m1;
        float w0j = W1[tid], w1j = W1[HDIM + tid];
        float mu  = m0*w0j + m1*w1j + b1[tid];
        float var = c00*w0j*w0j + 2.f*c01*w0j*w1j + c11*w1j*w1j;
        float aa  = gamma[tid] * rsqrtf(var + EPS_BN);
        s->a[tid]   = aa;
        s->bsh[tid] = beta[tid] - mu*aa;
        float v = 0.f;
        for (int m = 0; m < HDIM; ++m) v += Wg[tid*HDIM + m] * wf[m];
        s->v[tid]   = v;
        s->b1v[tid] = b1[tid];
        s->w0v[tid] = w0[tid];
        s->b2v[tid] = b2[tid];
    } else if (tid == HDIM) {
        float c = b0[0] + bf[0];
        for (int m = 0; m < HDIM; ++m) c += bg[m] * wf[m];
        s->c = c;
        s->alpha = alpha[0];
    }
    __syncthreads();
    const int nbn = (n + 255) >> 8;
    for (int cb = c0; cb < nbn; cb += cstride) {
        int i = cb * 256 + tid;
        if (i >= n) continue;
        float2 xv = ((const float2*)x)[i];
        float h[HDIM];
        #pragma unroll
        for (int j = 0; j < HDIM; ++j) {
            float t = xv.x*s->W1[j] + xv.y*s->W1[HDIM + j] + s->b1v[j];
            t = s->a[j]*t + s->bsh[j];
            h[j] = (t >= 0.f) ? t : s->alpha*t;
        }
        float em[HDIM];
        #pragma unroll
        for (int k = 0; k < HDIM; ++k) em[k] = s->b2v[k];
        #pragma unroll
        for (int j = 0; j < HDIM; ++j) {
            float hj = h[j];
            #pragma unroll
            for (int k = 0; k < HDIM; ++k) em[k] += hj * s->W2[j*HDIM + k];
        }
        float sdot = 0.f, ldot = 0.f;
        #pragma unroll
        for (int k = 0; k < HDIM; ++k) {
            sdot += em[k]*s->v[k]; ldot += em[k]*s->w0v[k];
        }
        sarr[i] = sdot;
        out[i]  = ldot + s->c;   // base; GCN terms added in finish
    }
}

// ---------------------------------------------------------------------------
// edge: 8 lanes/edge grid-stride; ew[e], atomic deg[dst]
// ---------------------------------------------------------------------------
__device__ __forceinline__
void edge_work(const uint4* __restrict__ rows, const float* __restrict__ scales,
               const int* __restrict__ src, const int* __restrict__ dst,
               float* __restrict__ ew, float* __restrict__ deg,
               int ne, int e0, int estride, int gl) {
    for (int e = e0; e < ne; e += estride) {
        int si = src[e], di = dst[e];
        const uint4* rs = rows + (size_t)si * 32;   // 32 uint4 = 512B row
        const uint4* rd = rows + (size_t)di * 32;
        uint4 A0 = rs[gl],      B0 = rd[gl];
        uint4 A1 = rs[gl + 8],  B1 = rd[gl + 8];
        uint4 A2 = rs[gl + 16], B2 = rd[gl + 16];
        uint4 A3 = rs[gl + 24], B3 = rd[gl + 24];
        int acc = dot4i8(A0.x,B0.x) + dot4i8(A0.y,B0.y) + dot4i8(A0.z,B0.z) + dot4i8(A0.w,B0.w)
                + dot4i8(A1.x,B1.x) + dot4i8(A1.y,B1.y) + dot4i8(A1.z,B1.z) + dot4i8(A1.w,B1.w)
                + dot4i8(A2.x,B2.x) + dot4i8(A2.y,B2.y) + dot4i8(A2.z,B2.z) + dot4i8(A2.w,B2.w)
                + dot4i8(A3.x,B3.x) + dot4i8(A3.y,B3.y) + dot4i8(A3.z,B3.z) + dot4i8(A3.w,B3.w);
        acc += __shfl_xor(acc, 4);
        acc += __shfl_xor(acc, 2);
        acc += __shfl_xor(acc, 1);
        if (gl == 0) {
            float w = (float)acc * scales[si] * scales[di];
            ew[e] = w;
            atomicAdd(&deg[di], w);
        }
    }
}

// ---------------------------------------------------------------------------
// finish: scatter + self-loop, grid-stride
// ---------------------------------------------------------------------------
__device__ __forceinline__
void finish_work(const int* __restrict__ src, const int* __restrict__ dst,
                 const float* __restrict__ ew, const float* __restrict__ deg,
                 const float* __restrict__ sarr, float* __restrict__ out,
                 int ne, int n, int t0, int tstride) {
    for (int t = t0; t < ne + n; t += tstride) {
        if (t < ne) {
            int si = src[t], di = dst[t];
            float w = ew[t] * rsqrtf((deg[si] + 1.f) * (deg[di] + 1.f)) * sarr[si];
            atomicAdd(&out[di], w);
        } else {
            int i = t - ne;
            atomicAdd(&out[i], sarr[i] / (deg[i] + 1.f));
        }
    }
}

// ---------------------------------------------------------------------------
// Cooperative fused kernel: 3 phases, 2 grid syncs, grid size = gridDim.x
// ---------------------------------------------------------------------------
__global__ __launch_bounds__(256, 4)
void k_fused(const float* __restrict__ face, const float* __restrict__ x,
             const int* __restrict__ src, const int* __restrict__ dst,
             const float* __restrict__ W1, const float* __restrict__ b1,
             const float* __restrict__ gamma, const float* __restrict__ beta,
             const float* __restrict__ alpha,
             const float* __restrict__ W2, const float* __restrict__ b2,
             const float* __restrict__ w0,
             const float* __restrict__ Wg, const float* __restrict__ bg,
             const float* __restrict__ wf,
             const float* __restrict__ b0, const float* __restrict__ bf,
             uint2* __restrict__ qrows, float* __restrict__ scales,
             float* __restrict__ deg, float* __restrict__ part,
             float* __restrict__ ew, float* __restrict__ sarr,
             float* __restrict__ out, int n, int ne) {
    cg::grid_group grid = cg::this_grid();
    const int tid = threadIdx.x;
    const int bid = (int)blockIdx.x;
    const int gb  = (int)gridDim.x;
    __shared__ NodeSmem ns;

    // Phase A: quant (all blocks, wave-stride) + xsums (blocks [0,NB_XS))
    quant_rows(face, qrows, scales, deg, n, bid*4 + (tid>>6), gb*4, tid & 63);
    if (bid < NB_XS) xsums_block(x, part, n, bid, tid);

    grid.sync();

    // Phase B: node role || edge role
    const int nbn   = (n + 255) >> 8;
    const int rnode = (nbn < (gb >> 2)) ? nbn : (gb >> 2);
    if (bid < rnode) {
        node_work(&ns, x, W1, b1, gamma, beta, alpha, W2, b2, w0,
                  Wg, bg, wf, b0, bf, part, sarr, out, n, tid, bid, rnode);
    } else {
        edge_work((const uint4*)qrows, scales, src, dst, ew, deg, ne,
                  (bid - rnode)*32 + (tid >> 3), (gb - rnode)*32, tid & 7);
    }

    grid.sync();

    // Phase C: finish
    finish_work(src, dst, ew, deg, sarr, out, ne, n, bid*256 + tid, gb*256);
}

// ---------------------------------------------------------------------------
// Fallback path (classic 3 launches) — identical math via the same helpers
// ---------------------------------------------------------------------------
__global__ __launch_bounds__(256)
void k_pA(const float* __restrict__ face, const float* __restrict__ x,
          uint2* __restrict__ qrows, float* __restrict__ scales,
          float* __restrict__ deg, float* __restrict__ part, int n, int qb) {
    int tid = threadIdx.x, bid = (int)blockIdx.x;
    if (bid < qb)
        quant_rows(face, qrows, scales, deg, n, bid*4 + (tid>>6), qb*4, tid & 63);
    else
        xsums_block(x, part, n, bid - qb, tid);
}

__global__ __launch_bounds__(256)
void k_pB(const float* __restrict__ x,
          const float* __restrict__ W1, const float* __restrict__ b1,
          const float* __restrict__ gamma, const float* __restrict__ beta,
          const float* __restrict__ alpha,
          const float* __restrict__ W2, const float* __restrict__ b2,
          const float* __restrict__ w0,
          const float* __restrict__ Wg, const float* __restrict__ bg,
          const float* __restrict__ wf,
          const float* __restrict__ b0, const float* __restrict__ bf,
          const float* __restrict__ part,
          const uint2* __restrict__ qrows, const float* __restrict__ scales,
          const int* __restrict__ src, const int* __restrict__ dst,
          float* __restrict__ ew, float* __restrict__ deg,
          float* __restrict__ sarr, float* __restrict__ out, int n, int ne) {
    int tid = threadIdx.x, bid = (int)blockIdx.x;
    const int nbn = (n + 255) >> 8;
    __shared__ NodeSmem ns;
    if (bid < nbn) {
        node_work(&ns, x, W1, b1, gamma, beta, alpha, W2, b2, w0,
                  Wg, bg, wf, b0, bf, part, sarr, out, n, tid, bid, nbn);
    } else {
        edge_work((const uint4*)qrows, scales, src, dst, ew, deg, ne,
                  (bid - nbn)*32 + (tid >> 3),
                  ((int)gridDim.x - nbn)*32, tid & 7);
    }
}

__global__ __launch_bounds__(256)
void k_pC(const int* __restrict__ src, const int* __restrict__ dst,
          const float* __restrict__ ew, const float* __restrict__ deg,
          const float* __restrict__ sarr, float* __restrict__ out,
          int ne, int n) {
    finish_work(src, dst, ew, deg, sarr, out, ne, n,
                (int)blockIdx.x*256 + (int)threadIdx.x,
                (int)gridDim.x*256);
}

// ---------------------------------------------------------------------------
extern "C" void kernel_launch(void* const* d_in, const int* in_sizes, int n_in,
                              void* d_out, int out_size, void* d_ws, size_t ws_size,
                              hipStream_t stream) {
    const float* x_p     = (const float*)d_in[0];
    const int*   ei      = (const int*)  d_in[1];
    const float* face_p  = (const float*)d_in[2];
    const float* W1_p    = (const float*)d_in[3];
    const float* b1_p    = (const float*)d_in[4];
    const float* gamma_p = (const float*)d_in[5];
    const float* beta_p  = (const float*)d_in[6];
    const float* alpha_p = (const float*)d_in[7];
    const float* W2_p    = (const float*)d_in[8];
    const float* b2_p    = (const float*)d_in[9];
    const float* w0_p    = (const float*)d_in[10];
    const float* b0_p    = (const float*)d_in[11];
    const float* Wg_p    = (const float*)d_in[12];
    const float* bg_p    = (const float*)d_in[13];
    const float* wf_p    = (const float*)d_in[14];
    const float* bf_p    = (const float*)d_in[15];

    int n  = in_sizes[0] / 2;   // 50000 nodes
    int ne = in_sizes[1] / 2;   // 160000 edges
    const int* src_p = ei;
    const int* dst_p = ei + ne;

    // workspace layout (floats). qrows first for 16B alignment.
    float*  ws       = (float*)d_ws;
    uint2*  qrows_p  = (uint2*)ws;                    // n*128 floats
    float*  after    = ws + (size_t)n * 128;
    float*  deg_p    = after;                         // [n]
    float*  scales_p = after + n;                     // [n]
    float*  sarr_p   = after + 2*(size_t)n;           // [n]
    float*  ew_p     = after + 3*(size_t)n;           // [ne]
    float*  part_p   = after + 3*(size_t)n + ne;      // [NB_XS*5]
    float*  out_p    = (float*)d_out;

    // --- try cooperative single-kernel path, sized by real occupancy ---
    int maxBlocksPerCU = 0;
    hipError_t qerr = hipOccupancyMaxActiveBlocksPerMultiprocessor(
        &maxBlocksPerCU, k_fused, 256, 0);
    int gb = (qerr == hipSuccess) ? maxBlocksPerCU * 256 : 0;  // 256 CUs
    if (gb > GB_MAX) gb = GB_MAX;

    hipError_t lerr = hipErrorUnknown;
    if (gb >= 256) {
        void* args[] = {
            (void*)&face_p, (void*)&x_p, (void*)&src_p, (void*)&dst_p,
            (void*)&W1_p, (void*)&b1_p, (void*)&gamma_p, (void*)&beta_p,
            (void*)&alpha_p, (void*)&W2_p, (void*)&b2_p, (void*)&w0_p,
            (void*)&Wg_p, (void*)&bg_p, (void*)&wf_p, (void*)&b0_p,
            (void*)&bf_p, (void*)&qrows_p, (void*)&scales_p, (void*)&deg_p,
            (void*)&part_p, (void*)&ew_p, (void*)&sarr_p, (void*)&out_p,
            (void*)&n, (void*)&ne
        };
        lerr = hipLaunchCooperativeKernel((void*)k_fused, dim3(gb), dim3(256),
                                          args, 0, stream);
    }

    if (lerr != hipSuccess) {
        // --- fallback: proven 3-kernel path (R6 structure) ---
        const int qb  = (n + 3) / 4;
        const int nbn = (n + 255) / 256;
        const int ebk = (ne + 31) / 32;
        k_pA<<<qb + NB_XS, 256, 0, stream>>>(face_p, x_p, qrows_p, scales_p,
                                             deg_p, part_p, n, qb);
        k_pB<<<nbn + ebk, 256, 0, stream>>>(x_p, W1_p, b1_p, gamma_p, beta_p,
                                            alpha_p, W2_p, b2_p, w0_p, Wg_p,
                                            bg_p, wf_p, b0_p, bf_p, part_p,
                                            qrows_p, scales_p, src_p, dst_p,
                                            ew_p, deg_p, sarr_p, out_p, n, ne);
        k_pC<<<(ne + n + 255) / 256, 256, 0, stream>>>(src_p, dst_p, ew_p,
                                                       deg_p, sarr_p, out_p,
                                                       ne, n);
    }
}

// Round 11
// 60.742 us; speedup vs baseline: 4.0158x; 4.0158x over previous
//
#include <hip/hip_runtime.h>

#define EPS_BN 1e-5f
#define FDIM 512        // face feature dim
#define F4   128        // FDIM/4
#define HDIM 32
#define NB_XS 64        // xsums partial blocks

// ---------------------------------------------------------------------------
__device__ __forceinline__ int dot4i8(unsigned a, unsigned b) {
#if __has_builtin(__builtin_amdgcn_sdot4)
    return __builtin_amdgcn_sdot4((int)a, (int)b, 0, false);
#else
    int s;
    s  = (int)(signed char)(a      ) * (int)(signed char)(b      );
    s += (int)(signed char)(a >>  8) * (int)(signed char)(b >>  8);
    s += (int)(signed char)(a >> 16) * (int)(signed char)(b >> 16);
    s += (int)(signed char)(a >> 24) * (int)(signed char)(b >> 24);
    return s;
#endif
}

struct NodeSmem {
    float W2[HDIM*HDIM];
    float W1[2*HDIM], b1v[HDIM], a[HDIM], bsh[HDIM];
    float v[HDIM], w0v[HDIM], b2v[HDIM];
    float c, alpha;
    float xsl[5];
};

// ---------------------------------------------------------------------------
// K_A: blocks [0,qb): quant one row per wave (+zero deg)
//      blocks [qb,qb+NB_XS): 5-scalar partial sums over x -> part (no atomics)
// ---------------------------------------------------------------------------
__global__ __launch_bounds__(256)
void k_pA(const float* __restrict__ face, const float* __restrict__ x,
          uint2* __restrict__ qrows, float* __restrict__ scales,
          float* __restrict__ deg, float* __restrict__ part, int n, int qb) {
    int tid = threadIdx.x, bid = (int)blockIdx.x;
    if (bid < qb) {
        // ---- quant: one wave per row ----
        int row  = bid * 4 + (tid >> 6);
        int lane = tid & 63;
        if (row >= n) return;
        const float4* f4 = (const float4*)face + (size_t)row * F4;
        float4 a = f4[lane];
        float4 b = f4[lane + 64];
        float ss = a.x*a.x + a.y*a.y + a.z*a.z + a.w*a.w
                 + b.x*b.x + b.y*b.y + b.z*b.z + b.w*b.w;
        float mx = fmaxf(fmaxf(fmaxf(fabsf(a.x), fabsf(a.y)),
                               fmaxf(fabsf(a.z), fabsf(a.w))),
                         fmaxf(fmaxf(fabsf(b.x), fabsf(b.y)),
                               fmaxf(fabsf(b.z), fabsf(b.w))));
        #pragma unroll
        for (int off = 32; off > 0; off >>= 1) {
            ss += __shfl_xor(ss, off);
            mx  = fmaxf(mx, __shfl_xor(mx, off));
        }
        float rn = rsqrtf(ss + 1e-12f);
        float qs = (mx > 0.f) ? 127.0f / mx : 0.f;
        unsigned da =  ((unsigned)(__float2int_rn(a.x*qs) & 255))
                    | (((unsigned)(__float2int_rn(a.y*qs) & 255)) << 8)
                    | (((unsigned)(__float2int_rn(a.z*qs) & 255)) << 16)
                    | (((unsigned)(__float2int_rn(a.w*qs) & 255)) << 24);
        unsigned db =  ((unsigned)(__float2int_rn(b.x*qs) & 255))
                    | (((unsigned)(__float2int_rn(b.y*qs) & 255)) << 8)
                    | (((unsigned)(__float2int_rn(b.z*qs) & 255)) << 16)
                    | (((unsigned)(__float2int_rn(b.w*qs) & 255)) << 24);
        qrows[(size_t)row * 64 + lane] = make_uint2(da, db);
        if (lane == 0) {
            scales[row] = mx * rn * (1.0f / 127.0f);
            deg[row]    = 0.f;
        }
    } else {
        // ---- xsums partials ----
        __shared__ float red[4][5];
        int xbid = bid - qb;
        float s0=0.f, s1=0.f, s00=0.f, s01=0.f, s11=0.f;
        for (int i = xbid * 256 + tid; i < n; i += NB_XS * 256) {
            float2 xv = ((const float2*)x)[i];
            s0  += xv.x;       s1  += xv.y;
            s00 += xv.x*xv.x;  s01 += xv.x*xv.y;  s11 += xv.y*xv.y;
        }
        #pragma unroll
        for (int off = 32; off > 0; off >>= 1) {
            s0  += __shfl_xor(s0,  off);
            s1  += __shfl_xor(s1,  off);
            s00 += __shfl_xor(s00, off);
            s01 += __shfl_xor(s01, off);
            s11 += __shfl_xor(s11, off);
        }
        int lane = tid & 63, w = tid >> 6;
        if (lane == 0) {
            red[w][0]=s0; red[w][1]=s1; red[w][2]=s00; red[w][3]=s01; red[w][4]=s11;
        }
        __syncthreads();
        if (tid < 5)
            part[xbid * 5 + tid] = red[0][tid] + red[1][tid]
                                 + red[2][tid] + red[3][tid];
    }
}

// ---------------------------------------------------------------------------
// K_B: blocks [0,nbn): node encoder (params recomputed per block from part)
//      blocks [nbn,..): edge dots — 8 lanes/edge, 32 edges/block, one pass
// ---------------------------------------------------------------------------
__global__ __launch_bounds__(256)
void k_pB(const float* __restrict__ x,
          const float* __restrict__ W1, const float* __restrict__ b1,
          const float* __restrict__ gamma, const float* __restrict__ beta,
          const float* __restrict__ alpha,
          const float* __restrict__ W2, const float* __restrict__ b2,
          const float* __restrict__ w0,
          const float* __restrict__ Wg, const float* __restrict__ bg,
          const float* __restrict__ wf,
          const float* __restrict__ b0, const float* __restrict__ bf,
          const float* __restrict__ part,
          const uint4* __restrict__ qrows, const float* __restrict__ scales,
          const int* __restrict__ src, const int* __restrict__ dst,
          float* __restrict__ ew, float* __restrict__ deg,
          float* __restrict__ sarr, float* __restrict__ out, int n, int ne) {
    int tid = threadIdx.x, bid = (int)blockIdx.x;
    const int nbn = (n + 255) >> 8;
    if (bid < nbn) {
        // ---- node role ----
        __shared__ NodeSmem s;
        for (int i = tid; i < HDIM*HDIM; i += 256) s.W2[i] = W2[i];
        if (tid < 2*HDIM) s.W1[tid] = W1[tid];
        if (tid < 5) {
            float acc = 0.f;
            for (int i = 0; i < NB_XS; ++i) acc += part[i * 5 + tid];
            s.xsl[tid] = acc;
        }
        __syncthreads();
        if (tid < HDIM) {
            float invN = 1.0f / (float)n;
            float m0 = s.xsl[0]*invN, m1 = s.xsl[1]*invN;
            float c00 = s.xsl[2]*invN - m0*m0;
            float c01 = s.xsl[3]*invN - m0*m1;
            float c11 = s.xsl[4]*invN - m1*m1;
            float w0j = W1[tid], w1j = W1[HDIM + tid];
            float mu  = m0*w0j + m1*w1j + b1[tid];
            float var = c00*w0j*w0j + 2.f*c01*w0j*w1j + c11*w1j*w1j;
            float aa  = gamma[tid] * rsqrtf(var + EPS_BN);
            s.a[tid]   = aa;
            s.bsh[tid] = beta[tid] - mu*aa;
            float v = 0.f;
            for (int m = 0; m < HDIM; ++m) v += Wg[tid*HDIM + m] * wf[m];
            s.v[tid]   = v;
            s.b1v[tid] = b1[tid];
            s.w0v[tid] = w0[tid];
            s.b2v[tid] = b2[tid];
        } else if (tid == HDIM) {
            float c = b0[0] + bf[0];
            for (int m = 0; m < HDIM; ++m) c += bg[m] * wf[m];
            s.c = c;
            s.alpha = alpha[0];
        }
        __syncthreads();
        int i = bid * 256 + tid;
        if (i >= n) return;
        float2 xv = ((const float2*)x)[i];
        float h[HDIM];
        #pragma unroll
        for (int j = 0; j < HDIM; ++j) {
            float t = xv.x*s.W1[j] + xv.y*s.W1[HDIM + j] + s.b1v[j];
            t = s.a[j]*t + s.bsh[j];
            h[j] = (t >= 0.f) ? t : s.alpha*t;
        }
        float em[HDIM];
        #pragma unroll
        for (int k = 0; k < HDIM; ++k) em[k] = s.b2v[k];
        #pragma unroll
        for (int j = 0; j < HDIM; ++j) {
            float hj = h[j];
            #pragma unroll
            for (int k = 0; k < HDIM; ++k) em[k] += hj * s.W2[j*HDIM + k];
        }
        float sdot = 0.f, ldot = 0.f;
        #pragma unroll
        for (int k = 0; k < HDIM; ++k) {
            sdot += em[k]*s.v[k]; ldot += em[k]*s.w0v[k];
        }
        sarr[i] = sdot;
        out[i]  = ldot + s.c;   // base; GCN terms added in k_pC
    } else {
        // ---- edge role: 8 lanes/edge, 32 edges/block ----
        int e  = (bid - nbn) * 32 + (tid >> 3);
        int gl = tid & 7;
        if (e >= ne) return;
        int si = src[e], di = dst[e];
        const uint4* rs = qrows + (size_t)si * 32;   // 32 uint4 = 512B row
        const uint4* rd = qrows + (size_t)di * 32;
        uint4 A0 = rs[gl],      B0 = rd[gl];
        uint4 A1 = rs[gl + 8],  B1 = rd[gl + 8];
        uint4 A2 = rs[gl + 16], B2 = rd[gl + 16];
        uint4 A3 = rs[gl + 24], B3 = rd[gl + 24];
        int acc = dot4i8(A0.x,B0.x) + dot4i8(A0.y,B0.y) + dot4i8(A0.z,B0.z) + dot4i8(A0.w,B0.w)
                + dot4i8(A1.x,B1.x) + dot4i8(A1.y,B1.y) + dot4i8(A1.z,B1.z) + dot4i8(A1.w,B1.w)
                + dot4i8(A2.x,B2.x) + dot4i8(A2.y,B2.y) + dot4i8(A2.z,B2.z) + dot4i8(A2.w,B2.w)
                + dot4i8(A3.x,B3.x) + dot4i8(A3.y,B3.y) + dot4i8(A3.z,B3.z) + dot4i8(A3.w,B3.w);
        acc += __shfl_xor(acc, 4);
        acc += __shfl_xor(acc, 2);
        acc += __shfl_xor(acc, 1);
        if (gl == 0) {
            float w = (float)acc * scales[si] * scales[di];
            ew[e] = w;
            atomicAdd(&deg[di], w);
        }
    }
}

// ---------------------------------------------------------------------------
// K_C: t<ne : out[dst] += ew*rsqrt((deg_s+1)(deg_d+1))*sarr[src]
//      t>=ne: out[i]   += sarr[i]/(deg[i]+1)   (self loop)
// ---------------------------------------------------------------------------
__global__ __launch_bounds__(256)
void k_pC(const int* __restrict__ src, const int* __restrict__ dst,
          const float* __restrict__ ew, const float* __restrict__ deg,
          const float* __restrict__ sarr, float* __restrict__ out,
          int ne, int n) {
    int t = (int)blockIdx.x * 256 + (int)threadIdx.x;
    if (t < ne) {
        int si = src[t], di = dst[t];
        float w = ew[t] * rsqrtf((deg[si] + 1.f) * (deg[di] + 1.f)) * sarr[si];
        atomicAdd(&out[di], w);
    } else if (t < ne + n) {
        int i = t - ne;
        atomicAdd(&out[i], sarr[i] / (deg[i] + 1.f));
    }
}

// ---------------------------------------------------------------------------
extern "C" void kernel_launch(void* const* d_in, const int* in_sizes, int n_in,
                              void* d_out, int out_size, void* d_ws, size_t ws_size,
                              hipStream_t stream) {
    const float* x_p     = (const float*)d_in[0];
    const int*   ei      = (const int*)  d_in[1];
    const float* face_p  = (const float*)d_in[2];
    const float* W1_p    = (const float*)d_in[3];
    const float* b1_p    = (const float*)d_in[4];
    const float* gamma_p = (const float*)d_in[5];
    const float* beta_p  = (const float*)d_in[6];
    const float* alpha_p = (const float*)d_in[7];
    const float* W2_p    = (const float*)d_in[8];
    const float* b2_p    = (const float*)d_in[9];
    const float* w0_p    = (const float*)d_in[10];
    const float* b0_p    = (const float*)d_in[11];
    const float* Wg_p    = (const float*)d_in[12];
    const float* bg_p    = (const float*)d_in[13];
    const float* wf_p    = (const float*)d_in[14];
    const float* bf_p    = (const float*)d_in[15];

    int n  = in_sizes[0] / 2;   // 50000 nodes
    int ne = in_sizes[1] / 2;   // 160000 edges
    const int* src_p = ei;
    const int* dst_p = ei + ne;

    // workspace layout (floats). qrows first for 16B alignment.
    float*  ws       = (float*)d_ws;
    uint2*  qrows_p  = (uint2*)ws;                    // n*128 floats
    float*  after    = ws + (size_t)n * 128;
    float*  deg_p    = after;                         // [n]
    float*  scales_p = after + n;                     // [n]
    float*  sarr_p   = after + 2*(size_t)n;           // [n]
    float*  ew_p     = after + 3*(size_t)n;           // [ne]
    float*  part_p   = after + 3*(size_t)n + ne;      // [NB_XS*5]
    float*  out_p    = (float*)d_out;

    const int qb  = (n + 3) / 4;          // quant blocks (4 rows/block)
    const int nbn = (n + 255) / 256;      // node blocks
    const int ebk = (ne + 31) / 32;       // edge blocks (32 edges/block)

    k_pA<<<qb + NB_XS, 256, 0, stream>>>(face_p, x_p, qrows_p, scales_p,
                                         deg_p, part_p, n, qb);
    k_pB<<<nbn + ebk, 256, 0, stream>>>(x_p, W1_p, b1_p, gamma_p, beta_p,
                                        alpha_p, W2_p, b2_p, w0_p, Wg_p,
                                        bg_p, wf_p, b0_p, bf_p, part_p,
                                        (const uint4*)qrows_p, scales_p,
                                        src_p, dst_p, ew_p, deg_p, sarr_p,
                                        out_p, n, ne);
    k_pC<<<(ne + n + 255) / 256, 256, 0, stream>>>(src_p, dst_p, ew_p, deg_p,
                                                   sarr_p, out_p, ne, n);
}